// Round 12
// baseline (338.727 us; speedup 1.0000x reference)
//
#include <hip/hip_runtime.h>
#include <hip/hip_cooperative_groups.h>
#include <math.h>

namespace cg = cooperative_groups;

#define BB 2
#define LL 2048
#define DD 256
#define PP 32
#define NC 64
#define PI_F 3.14159265358979323846f

typedef __attribute__((ext_vector_type(8))) short bf16x8;
typedef __attribute__((ext_vector_type(4))) float f32x4;
typedef unsigned short ushort_t;
typedef unsigned int uint_t;

__device__ inline ushort_t f2bf(float x) {
    uint_t u = __float_as_uint(x);
    uint_t r = (u + 0x7fffu + ((u >> 16) & 1u)) >> 16;
    return (ushort_t)r;
}

// ---------------------------------------------------------------------------
// Kernel A: prep (weight transposes to bf16 [N][K]) + encode_key (MFMA).
// blocks 0-31: W1^T; 32-63: W2^T; 64-79: Wo^T; 80-95: val_W^T;
// blocks 96-351: phases (16 rows each, MFMA K-split across 4 waves).
// ---------------------------------------------------------------------------
__global__ __launch_bounds__(256) void prep_key_kernel(
    const float* __restrict__ W1, const float* __restrict__ W2,
    const float* __restrict__ Wo, const float* __restrict__ valW,
    const float* __restrict__ x, const float* __restrict__ key_W,
    const float* __restrict__ key_b,
    ushort_t* __restrict__ W1t, ushort_t* __restrict__ W2t,
    ushort_t* __restrict__ Wot, ushort_t* __restrict__ valWt,
    float2* __restrict__ ph)
{
    const int bid = blockIdx.x;
    const int t = threadIdx.x;
    if (bid < 96) {
        __shared__ float T[64][65];
        const float* W; ushort_t* Wt; int K, N, tile;
        if (bid < 32)      { W = W1;   Wt = W1t;   K = 256; N = 512; tile = bid; }
        else if (bid < 64) { W = W2;   Wt = W2t;   K = 512; N = 256; tile = bid - 32; }
        else if (bid < 80) { W = Wo;   Wt = Wot;   K = 256; N = 256; tile = bid - 64; }
        else               { W = valW; Wt = valWt; K = 256; N = 256; tile = bid - 80; }
        const int ntiles = N / 64;
        const int k0 = (tile / ntiles) * 64, n0 = (tile % ntiles) * 64;
        {
            const int rr = t >> 2, cb = (t & 3) * 16;
            #pragma unroll
            for (int i = 0; i < 16; i += 4) {
                const float4 v = *(const float4*)&W[(k0 + rr) * N + n0 + cb + i];
                T[rr][cb + i + 0] = v.x; T[rr][cb + i + 1] = v.y;
                T[rr][cb + i + 2] = v.z; T[rr][cb + i + 3] = v.w;
            }
        }
        __syncthreads();
        {
            const int n = t >> 2, kb = (t & 3) * 16;
            #pragma unroll
            for (int i = 0; i < 16; ++i)
                Wt[(n0 + n) * K + k0 + kb + i] = f2bf(T[kb + i][n]);
        }
    } else {
        // ---- phases via MFMA ----
        __shared__ ushort_t xt[16][264];
        __shared__ ushort_t kwT[32][264];
        __shared__ float rbuf[4][2][16][17];
        const int row0 = (bid - 96) * 16;
        {
            const int l = t >> 4, cb = (t & 15) * 16;
            const float* src = &x[(long)(row0 + l) * DD + cb];
            ushort_t tmp[16];
            #pragma unroll
            for (int i = 0; i < 4; ++i) {
                const float4 v = *(const float4*)&src[i * 4];
                tmp[i*4+0] = f2bf(v.x); tmp[i*4+1] = f2bf(v.y);
                tmp[i*4+2] = f2bf(v.z); tmp[i*4+3] = f2bf(v.w);
            }
            *(uint4*)&xt[l][cb]     = *(uint4*)&tmp[0];
            *(uint4*)&xt[l][cb + 8] = *(uint4*)&tmp[8];
        }
        {
            #pragma unroll
            for (int i = 0; i < 8; ++i) {
                const int idx4 = i * 256 + t;
                const int k = idx4 >> 3, pc = (idx4 & 7) * 4;
                const float4 v = *(const float4*)&key_W[k * 32 + pc];
                kwT[pc + 0][k] = f2bf(v.x);
                kwT[pc + 1][k] = f2bf(v.y);
                kwT[pc + 2][k] = f2bf(v.z);
                kwT[pc + 3][k] = f2bf(v.w);
            }
        }
        __syncthreads();
        const int wv = t >> 6, lane = t & 63;
        const int qd = lane >> 4, mc = lane & 15;
        f32x4 acc0 = {0.f,0.f,0.f,0.f}, acc1 = {0.f,0.f,0.f,0.f};
        #pragma unroll
        for (int ks = 0; ks < 2; ++ks) {
            const int ko = wv * 64 + ks * 32 + qd * 8;
            const bf16x8 a  = *(const bf16x8*)&xt[mc][ko];
            const bf16x8 b0 = *(const bf16x8*)&kwT[mc][ko];
            const bf16x8 b1 = *(const bf16x8*)&kwT[16 + mc][ko];
            acc0 = __builtin_amdgcn_mfma_f32_16x16x32_bf16(a, b0, acc0, 0, 0, 0);
            acc1 = __builtin_amdgcn_mfma_f32_16x16x32_bf16(a, b1, acc1, 0, 0, 0);
        }
        #pragma unroll
        for (int r = 0; r < 4; ++r) {
            rbuf[wv][0][qd * 4 + r][mc] = acc0[r];
            rbuf[wv][1][qd * 4 + r][mc] = acc1[r];
        }
        __syncthreads();
        #pragma unroll
        for (int rep = 0; rep < 2; ++rep) {
            const int idx = rep * 256 + t;
            const int p = idx & 31, l = idx >> 5;
            const int nf = p >> 4, mcol = p & 15;
            float a = key_b[p] + rbuf[0][nf][l][mcol] + rbuf[1][nf][l][mcol]
                    + rbuf[2][nf][l][mcol] + rbuf[3][nf][l][mcol];
            a = tanhf(a) * PI_F;
            float sn, cs;
            sincosf(a, &sn, &cs);
            ph[(long)(row0 + l) * PP + p] = make_float2(cs, sn);
        }
    }
}

// ---------------------------------------------------------------------------
// Kernel B (cooperative): valbind -> grid.sync -> prefix -> grid.sync ->
// retrieve+LN1. Grid 512 x 256; LDS pool 74 KB -> 2 blocks/CU co-resident.
// ---------------------------------------------------------------------------
__global__ __launch_bounds__(256, 2) void middle_kernel(
    const float* __restrict__ x, const float* __restrict__ ph,
    const ushort_t* __restrict__ valWt, const float* __restrict__ val_b,
    ushort_t* __restrict__ VoddT, float* __restrict__ Mt,
    ushort_t* __restrict__ Mpre_b,
    const float* __restrict__ ln1_g, const float* __restrict__ ln1_b,
    ushort_t* __restrict__ rhat)
{
    __shared__ __align__(16) char smem[75776];
    cg::grid_group grid = cg::this_grid();
    const int tid = threadIdx.x;
    const int bid = blockIdx.x;
    const int wv = tid >> 6, lane = tid & 63;
    const int qd = lane >> 4, mc = lane & 15;

    // ================= Phase V: valbind (512 blocks) =================
    {
        ushort_t (*xsb)[264] = (ushort_t(*)[264])(smem);           // 8448
        ushort_t (*VdT)[40]  = (ushort_t(*)[40])(smem + 8448);     // 5120
        ushort_t (*phsT)[40] = (ushort_t(*)[40])(smem + 13568);    // 5120
        float    (*Ms)[68]   = (float(*)[68])(smem + 18688);       // 17408

        const int b  = bid >> 8;
        const int c  = (bid >> 2) & 63;
        const int dq = bid & 3;
        const int base = b * LL;
        const int r0 = 32 * c;

        {
            const int j = tid >> 4, cb = (tid & 15) * 16;
            const float* src = &x[(long)(base + r0 + 2 * j + 1) * DD + cb];
            ushort_t tmp[16];
            #pragma unroll
            for (int i = 0; i < 4; ++i) {
                const float4 v = *(const float4*)&src[i * 4];
                tmp[i*4+0] = f2bf(v.x); tmp[i*4+1] = f2bf(v.y);
                tmp[i*4+2] = f2bf(v.z); tmp[i*4+3] = f2bf(v.w);
            }
            *(uint4*)&xsb[j][cb]     = *(uint4*)&tmp[0];
            *(uint4*)&xsb[j][cb + 8] = *(uint4*)&tmp[8];
        }
        {
            const int j = tid >> 4, qb = (tid & 15) * 4;
            const float4 v = *(const float4*)&ph[(long)(base + r0 + 2 * j) * 64 + qb];
            phsT[qb + 0][j] = f2bf(v.x);
            phsT[qb + 1][j] = f2bf(v.y);
            phsT[qb + 2][j] = f2bf(v.z);
            phsT[qb + 3][j] = f2bf(v.w);
        }
        for (int e = tid; e < 64 * 16; e += 256) {
            phsT[e >> 4][16 + (e & 15)] = 0;
            VdT[e >> 4][16 + (e & 15)] = 0;
        }
        __syncthreads();

        f32x4 va = {0.f,0.f,0.f,0.f};
        const int dloc = wv * 16 + mc;
        const int ng = dq * 64 + dloc;
        const ushort_t* B0 = &valWt[(long)ng * 256];
        #pragma unroll
        for (int ks = 0; ks < 8; ++ks) {
            const bf16x8 a  = *(const bf16x8*)&xsb[mc][ks * 32 + qd * 8];
            const bf16x8 b0 = *(const bf16x8*)&B0[ks * 32 + qd * 8];
            va = __builtin_amdgcn_mfma_f32_16x16x32_bf16(a, b0, va, 0, 0, 0);
        }
        {
            const float bb = val_b[ng];
            #pragma unroll
            for (int r = 0; r < 4; ++r)
                VdT[dloc][qd * 4 + r] = f2bf(va[r] + bb);
        }
        __syncthreads();

        const bf16x8 a2 = *(const bf16x8*)&phsT[wv * 16 + mc][qd * 8];
        f32x4 macc[4];
        #pragma unroll
        for (int nf = 0; nf < 4; ++nf) {
            f32x4 z = {0.f,0.f,0.f,0.f};
            const bf16x8 b2 = *(const bf16x8*)&VdT[nf * 16 + mc][qd * 8];
            macc[nf] = __builtin_amdgcn_mfma_f32_16x16x32_bf16(a2, b2, z, 0, 0, 0);
        }
        #pragma unroll
        for (int nf = 0; nf < 4; ++nf) {
            #pragma unroll
            for (int r = 0; r < 4; ++r)
                Ms[nf * 16 + mc][wv * 16 + qd * 4 + r] = macc[nf][r];
        }
        __syncthreads();

        {
            float* dst = &Mt[((long)(b * NC + c) * 256 + dq * 64) * 64];
            #pragma unroll
            for (int p = 0; p < 4; ++p) {
                const int idx4 = p * 256 + tid;
                const int dl = idx4 >> 4, q4 = (idx4 & 15) * 4;
                *(float4*)&dst[dl * 64 + q4] = *(const float4*)&Ms[dl][q4];
            }
        }
        if (tid < 64) {
            ushort_t* vd = &VoddT[((long)(b * NC + c) * 256 + dq * 64 + tid) * 16];
            *(uint4*)&vd[0] = *(const uint4*)&VdT[tid][0];
            *(uint4*)&vd[8] = *(const uint4*)&VdT[tid][8];
        }
    }
    __threadfence();
    grid.sync();

    // ================= Phase P: prefix (512 blocks) =================
    {
        float (*segsum)[64] = (float(*)[64])(smem);
        const int b  = bid >> 8;
        const int cg2 = bid & 255;
        const int col = cg2 * 64 + (tid & 63);
        const int seg = tid >> 6;
        const long base = (long)b * NC * 16384 + col;

        float v[16], s = 0.f;
        #pragma unroll
        for (int i = 0; i < 16; ++i) {
            v[i] = Mt[base + (long)(seg * 16 + i) * 16384];
            s += v[i];
        }
        segsum[seg][tid & 63] = s;
        __syncthreads();
        float run = 0.f;
        #pragma unroll
        for (int sg = 0; sg < 3; ++sg)
            if (sg < seg) run += segsum[sg][tid & 63];
        #pragma unroll
        for (int i = 0; i < 16; ++i) {
            const long a = base + (long)(seg * 16 + i) * 16384;
            Mpre_b[a] = f2bf(run);
            run += v[i];
        }
    }
    __threadfence();
    grid.sync();

    // ================= Phase R: retrieve + LN1 (blocks 0..255) =================
    if (bid < 256) {
        ushort_t (*Bs_m)[72]  = (ushort_t(*)[72])(smem);           // 36864
        ushort_t (*Bs_v)[32]  = (ushort_t(*)[32])(smem + 36864);   // 16384
        ushort_t (*As_ph)[72] = (ushort_t(*)[72])(smem + 53248);   // 2304
        ushort_t (*Bs_sh)[72] = (ushort_t(*)[72])(smem + 55552);   // 2304
        ushort_t (*As_p)[32]  = (ushort_t(*)[32])(smem + 57856);   // 1024
        float    (*ref)[264]  = (float(*)[264])(smem + 58880);     // 16896

        const int b = bid >> 7;
        const int c = (bid >> 1) & 63;
        const int h = bid & 1;
        const int l0g = 32 * c + 16 * h;
        const long rowbase = (long)b * LL + l0g;

        {
            const ushort_t* src = &Mpre_b[(long)(b * NC + c) * 16384];
            #pragma unroll
            for (int p = 0; p < 8; ++p) {
                const int idx8 = p * 256 + tid;
                const int d = idx8 >> 3, q8 = (idx8 & 7) * 8;
                *(uint4*)&Bs_m[d][q8] = *(const uint4*)&src[idx8 * 8];
            }
        }
        {
            const int r = tid >> 4, q4 = (tid & 15) * 4;
            const float4 v = *(const float4*)&ph[(rowbase + r) * 64 + q4];
            ushort_t t0[4] = {f2bf(v.x), f2bf(v.y), f2bf(v.z), f2bf(v.w)};
            *(uint2*)&As_ph[r][q4] = *(uint2*)t0;
            const float4 w = *(const float4*)&ph[((long)b * LL + 32 * c + 2 * r) * 64 + q4];
            ushort_t t1[4] = {f2bf(w.x), f2bf(w.y), f2bf(w.z), f2bf(w.w)};
            *(uint2*)&Bs_sh[r][q4] = *(uint2*)t1;
        }
        {
            const ushort_t* src = &VoddT[(long)(b * NC + c) * 4096];
            const int j0 = (tid & 1) * 8;
            *(uint4*)&Bs_v[tid >> 1][j0] = *(const uint4*)&src[tid * 8];
            *(uint4*)&Bs_v[(tid + 256) >> 1][j0] = *(const uint4*)&src[(tid + 256) * 8];
            *(uint4*)&Bs_v[tid][16] = make_uint4(0, 0, 0, 0);
            *(uint4*)&Bs_v[tid][24] = make_uint4(0, 0, 0, 0);
            As_p[tid >> 4][16 + (tid & 15)] = 0;
        }
        __syncthreads();

        // S scores
        {
            f32x4 sacc = {0.f, 0.f, 0.f, 0.f};
            #pragma unroll
            for (int ks = 0; ks < 2; ++ks) {
                const bf16x8 a  = *(const bf16x8*)&As_ph[mc][ks * 32 + qd * 8];
                const bf16x8 bb = *(const bf16x8*)&Bs_sh[mc][ks * 32 + qd * 8];
                sacc = __builtin_amdgcn_mfma_f32_16x16x32_bf16(a, bb, sacc, 0, 0, 0);
            }
            if (wv == 0) {
                #pragma unroll
                for (int r = 0; r < 4; ++r) {
                    const int l = qd * 4 + r;
                    As_p[l][mc] = (2 * mc + 1 <= 16 * h + l) ? f2bf(sacc[r])
                                                             : (ushort_t)0;
                }
            }
        }

        // main contraction
        f32x4 acc[4];
        #pragma unroll
        for (int i = 0; i < 4; ++i) acc[i] = (f32x4){0.f, 0.f, 0.f, 0.f};
        #pragma unroll
        for (int i = 0; i < 4; ++i) {
            const int d0 = wv * 64 + i * 16;
            #pragma unroll
            for (int ks = 0; ks < 2; ++ks) {
                const bf16x8 a  = *(const bf16x8*)&As_ph[mc][ks * 32 + qd * 8];
                const bf16x8 bb = *(const bf16x8*)&Bs_m[d0 + mc][ks * 32 + qd * 8];
                acc[i] = __builtin_amdgcn_mfma_f32_16x16x32_bf16(a, bb, acc[i], 0, 0, 0);
            }
        }
        __syncthreads();

        // within-chunk correction
        {
            const bf16x8 a2 = *(const bf16x8*)&As_p[mc][qd * 8];
            #pragma unroll
            for (int i = 0; i < 4; ++i) {
                const int d0 = wv * 64 + i * 16;
                const bf16x8 b2 = *(const bf16x8*)&Bs_v[d0 + mc][qd * 8];
                acc[i] = __builtin_amdgcn_mfma_f32_16x16x32_bf16(a2, b2, acc[i], 0, 0, 0);
            }
        }

        // scale -> ref
        #pragma unroll
        for (int r = 0; r < 4; ++r) {
            const int l = qd * 4 + r;
            int va = (l0g + l + 1) >> 1; if (va < 1) va = 1;
            const float sc = 0.17677669529663687f * rsqrtf((float)va);
            #pragma unroll
            for (int i = 0; i < 4; ++i)
                ref[l][wv * 64 + i * 16 + mc] = acc[i][r] * sc;
        }
        __syncthreads();

        // LN1 -> rhat bf16
        {
            const int row = tid >> 4, cg2 = (tid & 15) * 16;
            float s = 0.f, sq = 0.f;
            #pragma unroll
            for (int i = 0; i < 16; ++i) {
                const float v = ref[row][cg2 + i];
                s += v; sq += v * v;
            }
            s += __shfl_xor(s, 1, 16);  sq += __shfl_xor(sq, 1, 16);
            s += __shfl_xor(s, 2, 16);  sq += __shfl_xor(sq, 2, 16);
            s += __shfl_xor(s, 4, 16);  sq += __shfl_xor(sq, 4, 16);
            s += __shfl_xor(s, 8, 16);  sq += __shfl_xor(sq, 8, 16);
            const float m = s * (1.f / 256.f);
            const float inv = rsqrtf(sq * (1.f / 256.f) - m * m + 1e-5f);
            ushort_t o16[16];
            #pragma unroll
            for (int i = 0; i < 16; ++i) {
                const int cc = cg2 + i;
                o16[i] = f2bf((ref[row][cc] - m) * inv * ln1_g[cc] + ln1_b[cc]);
            }
            ushort_t* dst = &rhat[(rowbase + row) * DD + cg2];
            *(uint4*)&dst[0] = *(uint4*)&o16[0];
            *(uint4*)&dst[8] = *(uint4*)&o16[8];
        }
    }
}

// ---------------------------------------------------------------------------
// gemm1: h = gelu(rhat @ W1^T + b1). BM=32, grid 1024.  (R10 version)
// ---------------------------------------------------------------------------
__global__ __launch_bounds__(256) void gemm1_kernel(
    const ushort_t* __restrict__ A, const ushort_t* __restrict__ Bt,
    const float* __restrict__ bias, ushort_t* __restrict__ out)
{
    __shared__ ushort_t As[32][136];
    __shared__ ushort_t Bs[64][136];
    const int tid = threadIdx.x;
    const int mt = blockIdx.x & 127;
    const int nt = blockIdx.x >> 7;
    const int m0 = mt * 32, n0 = nt * 64;
    const int wv = tid >> 6, lane = tid & 63;
    const int qd = lane >> 4, mc = lane & 15;

    f32x4 acc0 = {0.f, 0.f, 0.f, 0.f};
    f32x4 acc1 = {0.f, 0.f, 0.f, 0.f};

    const int ar = tid >> 3, ak = (tid & 7) * 16;
    const int bn = tid >> 2, bk = (tid & 3) * 32;

    for (int k0 = 0; k0 < 256; k0 += 128) {
        __syncthreads();
        {
            const ushort_t* sa = &A[(long)(m0 + ar) * 256 + k0 + ak];
            *(uint4*)&As[ar][ak]     = *(const uint4*)&sa[0];
            *(uint4*)&As[ar][ak + 8] = *(const uint4*)&sa[8];
        }
        {
            const ushort_t* src = &Bt[(long)(n0 + bn) * 256 + k0 + bk];
            *(uint4*)&Bs[bn][bk +  0] = *(const uint4*)&src[0];
            *(uint4*)&Bs[bn][bk +  8] = *(const uint4*)&src[8];
            *(uint4*)&Bs[bn][bk + 16] = *(const uint4*)&src[16];
            *(uint4*)&Bs[bn][bk + 24] = *(const uint4*)&src[24];
        }
        __syncthreads();
        #pragma unroll
        for (int ko = 0; ko < 128; ko += 32) {
            const bf16x8 a0 = *(const bf16x8*)&As[mc][ko + qd * 8];
            const bf16x8 a1 = *(const bf16x8*)&As[16 + mc][ko + qd * 8];
            const bf16x8 b  = *(const bf16x8*)&Bs[wv * 16 + mc][ko + qd * 8];
            acc0 = __builtin_amdgcn_mfma_f32_16x16x32_bf16(a0, b, acc0, 0, 0, 0);
            acc1 = __builtin_amdgcn_mfma_f32_16x16x32_bf16(a1, b, acc1, 0, 0, 0);
        }
    }

    const int nn = n0 + wv * 16 + mc;
    const float bb = bias[nn];
    #pragma unroll
    for (int r = 0; r < 4; ++r) {
        const long row0w = m0 + qd * 4 + r;
        float v0 = acc0[r] + bb;
        float v1 = acc1[r] + bb;
        v0 = 0.5f * v0 * (1.f + erff(v0 * 0.70710678118654752f));
        v1 = 0.5f * v1 * (1.f + erff(v1 * 0.70710678118654752f));
        out[row0w * 512 + nn] = f2bf(v0);
        out[(row0w + 16) * 512 + nn] = f2bf(v1);
    }
}

// ---------------------------------------------------------------------------
// Kernel F: gemm2 + LN2 + gemm3 fused. BM=16, grid 256.  (R10 version)
// ---------------------------------------------------------------------------
__global__ __launch_bounds__(256) void gemm23_kernel(
    const ushort_t* __restrict__ h, const ushort_t* __restrict__ W2t,
    const float* __restrict__ b2, const float* __restrict__ ln2_g,
    const float* __restrict__ ln2_b, const ushort_t* __restrict__ Wot,
    const float* __restrict__ bo, const float* __restrict__ x,
    float* __restrict__ out)
{
    __shared__ ushort_t As[16][72];
    __shared__ ushort_t Bs[256][72];
    __shared__ float Ct[16][264];
    __shared__ ushort_t shT[16][264];

    const int tid = threadIdx.x;
    const int m0 = blockIdx.x * 16;
    const int wv = tid >> 6, lane = tid & 63;
    const int qd = lane >> 4, mc = lane & 15;

    f32x4 acc[4];
    #pragma unroll
    for (int nf = 0; nf < 4; ++nf) acc[nf] = (f32x4){0.f,0.f,0.f,0.f};

    const int sr = tid >> 3, sk = (tid & 7) * 8;

    for (int k0 = 0; k0 < 512; k0 += 64) {
        __syncthreads();
        if (tid < 128)
            *(uint4*)&As[sr][sk] = *(const uint4*)&h[(long)(m0 + sr) * 512 + k0 + sk];
        #pragma unroll
        for (int rr = 0; rr < 8; ++rr) {
            const int n = rr * 32 + (tid >> 3);
            *(uint4*)&Bs[n][sk] = *(const uint4*)&W2t[(long)n * 512 + k0 + sk];
        }
        __syncthreads();
        #pragma unroll
        for (int ks = 0; ks < 2; ++ks) {
            const bf16x8 a = *(const bf16x8*)&As[mc][ks * 32 + qd * 8];
            #pragma unroll
            for (int nf = 0; nf < 4; ++nf) {
                const bf16x8 b = *(const bf16x8*)&Bs[wv * 64 + nf * 16 + mc][ks * 32 + qd * 8];
                acc[nf] = __builtin_amdgcn_mfma_f32_16x16x32_bf16(a, b, acc[nf], 0, 0, 0);
            }
        }
    }

    #pragma unroll
    for (int nf = 0; nf < 4; ++nf) {
        const int n = wv * 64 + nf * 16 + mc;
        const float bb = b2[n];
        #pragma unroll
        for (int r = 0; r < 4; ++r)
            Ct[qd * 4 + r][n] = acc[nf][r] + bb;
    }
    __syncthreads();

    {
        const int row = tid >> 4, cg2 = (tid & 15) * 16;
        float s = 0.f, sq = 0.f;
        #pragma unroll
        for (int i = 0; i < 16; ++i) {
            const float v = Ct[row][cg2 + i];
            s += v; sq += v * v;
        }
        s  += __shfl_xor(s, 1, 16);  sq += __shfl_xor(sq, 1, 16);
        s  += __shfl_xor(s, 2, 16);  sq += __shfl_xor(sq, 2, 16);
        s  += __shfl_xor(s, 4, 16);  sq += __shfl_xor(sq, 4, 16);
        s  += __shfl_xor(s, 8, 16);  sq += __shfl_xor(sq, 8, 16);
        const float m = s * (1.f / 256.f);
        const float inv = rsqrtf(sq * (1.f / 256.f) - m * m + 1e-5f);
        #pragma unroll
        for (int i = 0; i < 16; ++i) {
            const int cc = cg2 + i;
            shT[row][cc] = f2bf((Ct[row][cc] - m) * inv * ln2_g[cc] + ln2_b[cc]);
        }
    }

    f32x4 acc2[4];
    #pragma unroll
    for (int nf = 0; nf < 4; ++nf) acc2[nf] = (f32x4){0.f,0.f,0.f,0.f};

    for (int k0 = 0; k0 < 256; k0 += 64) {
        __syncthreads();
        #pragma unroll
        for (int rr = 0; rr < 8; ++rr) {
            const int n = rr * 32 + (tid >> 3);
            *(uint4*)&Bs[n][sk] = *(const uint4*)&Wot[(long)n * 256 + k0 + sk];
        }
        __syncthreads();
        #pragma unroll
        for (int ks = 0; ks < 2; ++ks) {
            const bf16x8 a = *(const bf16x8*)&shT[mc][k0 + ks * 32 + qd * 8];
            #pragma unroll
            for (int nf = 0; nf < 4; ++nf) {
                const bf16x8 b = *(const bf16x8*)&Bs[wv * 64 + nf * 16 + mc][ks * 32 + qd * 8];
                acc2[nf] = __builtin_amdgcn_mfma_f32_16x16x32_bf16(a, b, acc2[nf], 0, 0, 0);
            }
        }
    }

    #pragma unroll
    for (int nf = 0; nf < 4; ++nf) {
        const int n = wv * 64 + nf * 16 + mc;
        const float bb = bo[n];
        #pragma unroll
        for (int r = 0; r < 4; ++r) {
            const long row = m0 + qd * 4 + r;
            out[row * DD + n] = acc2[nf][r] + bb + x[row * DD + n];
        }
    }
}

// ---------------------------------------------------------------------------
extern "C" void kernel_launch(void* const* d_in, const int* in_sizes, int n_in,
                              void* d_out, int out_size, void* d_ws, size_t ws_size,
                              hipStream_t stream)
{
    const float* x     = (const float*)d_in[0];
    const float* key_W = (const float*)d_in[1];
    const float* key_b = (const float*)d_in[2];
    const float* val_W = (const float*)d_in[3];
    const float* val_b = (const float*)d_in[4];
    const float* ln1_g = (const float*)d_in[5];
    const float* ln1_b = (const float*)d_in[6];
    const float* W1    = (const float*)d_in[7];
    const float* b1    = (const float*)d_in[8];
    const float* W2    = (const float*)d_in[9];
    const float* b2    = (const float*)d_in[10];
    const float* ln2_g = (const float*)d_in[11];
    const float* ln2_b = (const float*)d_in[12];
    const float* Wo    = (const float*)d_in[13];
    const float* bo    = (const float*)d_in[14];
    float* outp = (float*)d_out;

    float* ws = (float*)d_ws;
    float*  ph       = ws;                            // 262144 f32 (1 MB)
    float*  Mt       = ws + 262144;                   // 2097152 f32 (8 MB)
    ushort_t* Mpre_b = (ushort_t*)(Mt + 2097152);     // 2097152 us (4 MB)
    ushort_t* VoddT  = Mpre_b + 2097152;              // 524288 us (1 MB)
    ushort_t* rhat_b = VoddT + 524288;                // 1048576 us (2 MB)
    ushort_t* W1t    = rhat_b + 1048576;              // 131072 us
    ushort_t* W2t    = W1t + 131072;
    ushort_t* Wot    = W2t + 131072;
    ushort_t* valWt  = Wot + 65536;
    // reuse Mt after middle_kernel:
    ushort_t* h_b    = (ushort_t*)Mt;                 // 4096x512 bf16 (4 MB)

    prep_key_kernel<<<352, 256, 0, stream>>>(W1, W2, Wo, val_W, x, key_W, key_b,
                                             W1t, W2t, Wot, valWt, (float2*)ph);
    {
        void* cargs[] = {(void*)&x, (void*)&ph, (void*)&valWt, (void*)&val_b,
                         (void*)&VoddT, (void*)&Mt, (void*)&Mpre_b,
                         (void*)&ln1_g, (void*)&ln1_b, (void*)&rhat_b};
        hipLaunchCooperativeKernel((void*)middle_kernel, dim3(512), dim3(256),
                                   cargs, 0, stream);
    }
    gemm1_kernel<<<1024, 256, 0, stream>>>(rhat_b, W1t, b1, h_b);
    gemm23_kernel<<<256, 256, 0, stream>>>(h_b, W2t, b2, ln2_g, ln2_b,
                                           Wot, bo, x, outp);
}

// Round 13
// 125.010 us; speedup vs baseline: 2.7096x; 2.7096x over previous
//
#include <hip/hip_runtime.h>
#include <math.h>

#define BB 2
#define LL 2048
#define DD 256
#define PP 32
#define NC 64
#define PI_F 3.14159265358979323846f

typedef __attribute__((ext_vector_type(8))) short bf16x8;
typedef __attribute__((ext_vector_type(4))) float f32x4;
typedef unsigned short ushort_t;
typedef unsigned int uint_t;

__device__ inline ushort_t f2bf(float x) {
    uint_t u = __float_as_uint(x);
    uint_t r = (u + 0x7fffu + ((u >> 16) & 1u)) >> 16;
    return (ushort_t)r;
}
__device__ inline float bf2f(ushort_t u) {
    return __uint_as_float(((uint_t)u) << 16);
}

// ---------------------------------------------------------------------------
// Kernel A: prep (weight transposes to bf16 [N][K]) + encode_key (MFMA).
// blocks 0-31: W1^T; 32-63: W2^T; 64-79: Wo^T; 80-95: val_W^T;
// blocks 96-351: phases (16 rows each, MFMA K-split across 4 waves).
// ---------------------------------------------------------------------------
__global__ __launch_bounds__(256) void prep_key_kernel(
    const float* __restrict__ W1, const float* __restrict__ W2,
    const float* __restrict__ Wo, const float* __restrict__ valW,
    const float* __restrict__ x, const float* __restrict__ key_W,
    const float* __restrict__ key_b,
    ushort_t* __restrict__ W1t, ushort_t* __restrict__ W2t,
    ushort_t* __restrict__ Wot, ushort_t* __restrict__ valWt,
    float2* __restrict__ ph)
{
    const int bid = blockIdx.x;
    const int t = threadIdx.x;
    if (bid < 96) {
        __shared__ float T[64][65];
        const float* W; ushort_t* Wt; int K, N, tile;
        if (bid < 32)      { W = W1;   Wt = W1t;   K = 256; N = 512; tile = bid; }
        else if (bid < 64) { W = W2;   Wt = W2t;   K = 512; N = 256; tile = bid - 32; }
        else if (bid < 80) { W = Wo;   Wt = Wot;   K = 256; N = 256; tile = bid - 64; }
        else               { W = valW; Wt = valWt; K = 256; N = 256; tile = bid - 80; }
        const int ntiles = N / 64;
        const int k0 = (tile / ntiles) * 64, n0 = (tile % ntiles) * 64;
        {
            const int rr = t >> 2, cb = (t & 3) * 16;
            #pragma unroll
            for (int i = 0; i < 16; i += 4) {
                const float4 v = *(const float4*)&W[(k0 + rr) * N + n0 + cb + i];
                T[rr][cb + i + 0] = v.x; T[rr][cb + i + 1] = v.y;
                T[rr][cb + i + 2] = v.z; T[rr][cb + i + 3] = v.w;
            }
        }
        __syncthreads();
        {
            const int n = t >> 2, kb = (t & 3) * 16;
            #pragma unroll
            for (int i = 0; i < 16; ++i)
                Wt[(n0 + n) * K + k0 + kb + i] = f2bf(T[kb + i][n]);
        }
    } else {
        // ---- phases via MFMA ----
        __shared__ ushort_t xt[16][264];
        __shared__ ushort_t kwT[32][264];
        __shared__ float rbuf[4][2][16][17];
        const int row0 = (bid - 96) * 16;
        {
            const int l = t >> 4, cb = (t & 15) * 16;
            const float* src = &x[(long)(row0 + l) * DD + cb];
            ushort_t tmp[16];
            #pragma unroll
            for (int i = 0; i < 4; ++i) {
                const float4 v = *(const float4*)&src[i * 4];
                tmp[i*4+0] = f2bf(v.x); tmp[i*4+1] = f2bf(v.y);
                tmp[i*4+2] = f2bf(v.z); tmp[i*4+3] = f2bf(v.w);
            }
            *(uint4*)&xt[l][cb]     = *(uint4*)&tmp[0];
            *(uint4*)&xt[l][cb + 8] = *(uint4*)&tmp[8];
        }
        {
            #pragma unroll
            for (int i = 0; i < 8; ++i) {
                const int idx4 = i * 256 + t;
                const int k = idx4 >> 3, pc = (idx4 & 7) * 4;
                const float4 v = *(const float4*)&key_W[k * 32 + pc];
                kwT[pc + 0][k] = f2bf(v.x);
                kwT[pc + 1][k] = f2bf(v.y);
                kwT[pc + 2][k] = f2bf(v.z);
                kwT[pc + 3][k] = f2bf(v.w);
            }
        }
        __syncthreads();
        const int wv = t >> 6, lane = t & 63;
        const int qd = lane >> 4, mc = lane & 15;
        f32x4 acc0 = {0.f,0.f,0.f,0.f}, acc1 = {0.f,0.f,0.f,0.f};
        #pragma unroll
        for (int ks = 0; ks < 2; ++ks) {
            const int ko = wv * 64 + ks * 32 + qd * 8;
            const bf16x8 a  = *(const bf16x8*)&xt[mc][ko];
            const bf16x8 b0 = *(const bf16x8*)&kwT[mc][ko];
            const bf16x8 b1 = *(const bf16x8*)&kwT[16 + mc][ko];
            acc0 = __builtin_amdgcn_mfma_f32_16x16x32_bf16(a, b0, acc0, 0, 0, 0);
            acc1 = __builtin_amdgcn_mfma_f32_16x16x32_bf16(a, b1, acc1, 0, 0, 0);
        }
        #pragma unroll
        for (int r = 0; r < 4; ++r) {
            rbuf[wv][0][qd * 4 + r][mc] = acc0[r];
            rbuf[wv][1][qd * 4 + r][mc] = acc1[r];
        }
        __syncthreads();
        #pragma unroll
        for (int rep = 0; rep < 2; ++rep) {
            const int idx = rep * 256 + t;
            const int p = idx & 31, l = idx >> 5;
            const int nf = p >> 4, mcol = p & 15;
            float a = key_b[p] + rbuf[0][nf][l][mcol] + rbuf[1][nf][l][mcol]
                    + rbuf[2][nf][l][mcol] + rbuf[3][nf][l][mcol];
            a = tanhf(a) * PI_F;
            float sn, cs;
            sincosf(a, &sn, &cs);
            ph[(long)(row0 + l) * PP + p] = make_float2(cs, sn);
        }
    }
}

// ---------------------------------------------------------------------------
// Kernel B: valbind. Block = (b, chunk c, d-quarter dq); grid 512.
// Mt now stored bf16.
// ---------------------------------------------------------------------------
__global__ __launch_bounds__(256) void valbind_kernel(
    const float* __restrict__ x, const float2* __restrict__ ph,
    const ushort_t* __restrict__ valWt, const float* __restrict__ val_b,
    ushort_t* __restrict__ VoddT, ushort_t* __restrict__ Mt)
{
    __shared__ ushort_t xsb[16][264];
    __shared__ ushort_t VdT[64][40];
    __shared__ ushort_t phsT[64][40];
    __shared__ float    Ms[64][68];

    const int tid = threadIdx.x;
    const int bid = blockIdx.x;
    const int b  = bid >> 8;
    const int c  = (bid >> 2) & 63;
    const int dq = bid & 3;
    const int base = b * LL;
    const int r0 = 32 * c;

    {
        const int j = tid >> 4, cb = (tid & 15) * 16;
        const float* src = &x[(long)(base + r0 + 2 * j + 1) * DD + cb];
        ushort_t tmp[16];
        #pragma unroll
        for (int i = 0; i < 4; ++i) {
            const float4 v = *(const float4*)&src[i * 4];
            tmp[i*4+0] = f2bf(v.x); tmp[i*4+1] = f2bf(v.y);
            tmp[i*4+2] = f2bf(v.z); tmp[i*4+3] = f2bf(v.w);
        }
        *(uint4*)&xsb[j][cb]     = *(uint4*)&tmp[0];
        *(uint4*)&xsb[j][cb + 8] = *(uint4*)&tmp[8];
    }
    {
        const int j = tid >> 4, qb = (tid & 15) * 4;
        const float4 v = *(const float4*)((const float*)ph +
                              (long)(base + r0 + 2 * j) * 64 + qb);
        phsT[qb + 0][j] = f2bf(v.x);
        phsT[qb + 1][j] = f2bf(v.y);
        phsT[qb + 2][j] = f2bf(v.z);
        phsT[qb + 3][j] = f2bf(v.w);
    }
    for (int e = tid; e < 64 * 16; e += 256) {
        phsT[e >> 4][16 + (e & 15)] = 0;
        VdT[e >> 4][16 + (e & 15)] = 0;
    }
    __syncthreads();

    const int wv = tid >> 6, lane = tid & 63;
    const int qd = lane >> 4, mc = lane & 15;

    f32x4 va = {0.f,0.f,0.f,0.f};
    const int dloc = wv * 16 + mc;
    const int ng = dq * 64 + dloc;
    const ushort_t* B0 = &valWt[(long)ng * 256];
    #pragma unroll
    for (int ks = 0; ks < 8; ++ks) {
        const bf16x8 a  = *(const bf16x8*)&xsb[mc][ks * 32 + qd * 8];
        const bf16x8 b0 = *(const bf16x8*)&B0[ks * 32 + qd * 8];
        va = __builtin_amdgcn_mfma_f32_16x16x32_bf16(a, b0, va, 0, 0, 0);
    }
    {
        const float bb = val_b[ng];
        #pragma unroll
        for (int r = 0; r < 4; ++r)
            VdT[dloc][qd * 4 + r] = f2bf(va[r] + bb);
    }
    __syncthreads();

    const bf16x8 a2 = *(const bf16x8*)&phsT[wv * 16 + mc][qd * 8];
    f32x4 macc[4];
    #pragma unroll
    for (int nf = 0; nf < 4; ++nf) {
        f32x4 z = {0.f,0.f,0.f,0.f};
        const bf16x8 b2 = *(const bf16x8*)&VdT[nf * 16 + mc][qd * 8];
        macc[nf] = __builtin_amdgcn_mfma_f32_16x16x32_bf16(a2, b2, z, 0, 0, 0);
    }
    #pragma unroll
    for (int nf = 0; nf < 4; ++nf) {
        #pragma unroll
        for (int r = 0; r < 4; ++r)
            Ms[nf * 16 + mc][wv * 16 + qd * 4 + r] = macc[nf][r];
    }
    __syncthreads();

    {   // dump Ms -> Mt (bf16, coalesced 8B/thread)
        ushort_t* dst = &Mt[((long)(b * NC + c) * 256 + dq * 64) * 64];
        #pragma unroll
        for (int p = 0; p < 4; ++p) {
            const int idx4 = p * 256 + tid;
            const int dl = idx4 >> 4, q4 = (idx4 & 15) * 4;
            const float4 v = *(const float4*)&Ms[dl][q4];
            ushort_t tmp[4] = {f2bf(v.x), f2bf(v.y), f2bf(v.z), f2bf(v.w)};
            *(uint2*)&dst[dl * 64 + q4] = *(uint2*)tmp;
        }
    }
    if (tid < 64) {
        ushort_t* vd = &VoddT[((long)(b * NC + c) * 256 + dq * 64 + tid) * 16];
        *(uint4*)&vd[0] = *(const uint4*)&VdT[tid][0];
        *(uint4*)&vd[8] = *(const uint4*)&VdT[tid][8];
    }
}

// ---------------------------------------------------------------------------
// Kernel C: prefix. EXCLUSIVE scan of Mt (bf16) over chunk c -> bf16 Mpre_b.
// ---------------------------------------------------------------------------
__global__ __launch_bounds__(256) void prefix_kernel(
    const ushort_t* __restrict__ M, ushort_t* __restrict__ Mpre_b)
{
    __shared__ float segsum[4][64];
    const int tid = threadIdx.x;
    const int b  = blockIdx.x >> 8;
    const int cg = blockIdx.x & 255;
    const int col = cg * 64 + (tid & 63);
    const int seg = tid >> 6;
    const long base = (long)b * NC * 16384 + col;

    float v[16], s = 0.f;
    #pragma unroll
    for (int i = 0; i < 16; ++i) {
        v[i] = bf2f(M[base + (long)(seg * 16 + i) * 16384]);
        s += v[i];
    }
    segsum[seg][tid & 63] = s;
    __syncthreads();
    float run = 0.f;
    #pragma unroll
    for (int sg = 0; sg < 3; ++sg)
        if (sg < seg) run += segsum[sg][tid & 63];
    #pragma unroll
    for (int i = 0; i < 16; ++i) {
        const long a = base + (long)(seg * 16 + i) * 16384;
        Mpre_b[a] = f2bf(run);
        run += v[i];
    }
}

// ---------------------------------------------------------------------------
// Kernel D: retrieve (MFMA) + LN1 -> rhat (bf16). Grid 256.
// ---------------------------------------------------------------------------
__global__ __launch_bounds__(256) void retrieve_kernel(
    const float* __restrict__ ph, const ushort_t* __restrict__ Mpre_b,
    const ushort_t* __restrict__ VoddT,
    const float* __restrict__ ln1_g, const float* __restrict__ ln1_b,
    ushort_t* __restrict__ rhat)
{
    __shared__ ushort_t Bs_m[256][72];
    __shared__ ushort_t Bs_v[256][32];
    __shared__ ushort_t As_ph[16][72];
    __shared__ ushort_t Bs_sh[16][72];
    __shared__ ushort_t As_p[16][32];
    __shared__ float    ref[16][264];

    const int tid = threadIdx.x;
    const int b = blockIdx.x >> 7;
    const int c = (blockIdx.x >> 1) & 63;
    const int h = blockIdx.x & 1;
    const int l0g = 32 * c + 16 * h;
    const long rowbase = (long)b * LL + l0g;

    {
        const ushort_t* src = &Mpre_b[(long)(b * NC + c) * 16384];
        #pragma unroll
        for (int p = 0; p < 8; ++p) {
            const int idx8 = p * 256 + tid;
            const int d = idx8 >> 3, q8 = (idx8 & 7) * 8;
            *(uint4*)&Bs_m[d][q8] = *(const uint4*)&src[idx8 * 8];
        }
    }
    {
        const int r = tid >> 4, q4 = (tid & 15) * 4;
        const float4 v = *(const float4*)&ph[(rowbase + r) * 64 + q4];
        ushort_t t0[4] = {f2bf(v.x), f2bf(v.y), f2bf(v.z), f2bf(v.w)};
        *(uint2*)&As_ph[r][q4] = *(uint2*)t0;
        const float4 w = *(const float4*)&ph[((long)b * LL + 32 * c + 2 * r) * 64 + q4];
        ushort_t t1[4] = {f2bf(w.x), f2bf(w.y), f2bf(w.z), f2bf(w.w)};
        *(uint2*)&Bs_sh[r][q4] = *(uint2*)t1;
    }
    {
        const ushort_t* src = &VoddT[(long)(b * NC + c) * 4096];
        const int j0 = (tid & 1) * 8;
        *(uint4*)&Bs_v[tid >> 1][j0] = *(const uint4*)&src[tid * 8];
        *(uint4*)&Bs_v[(tid + 256) >> 1][j0] = *(const uint4*)&src[(tid + 256) * 8];
        *(uint4*)&Bs_v[tid][16] = make_uint4(0, 0, 0, 0);
        *(uint4*)&Bs_v[tid][24] = make_uint4(0, 0, 0, 0);
        As_p[tid >> 4][16 + (tid & 15)] = 0;
    }
    __syncthreads();

    const int wv = tid >> 6, lane = tid & 63;
    const int qd = lane >> 4, mc = lane & 15;

    // S scores
    {
        f32x4 sacc = {0.f, 0.f, 0.f, 0.f};
        #pragma unroll
        for (int ks = 0; ks < 2; ++ks) {
            const bf16x8 a  = *(const bf16x8*)&As_ph[mc][ks * 32 + qd * 8];
            const bf16x8 bb = *(const bf16x8*)&Bs_sh[mc][ks * 32 + qd * 8];
            sacc = __builtin_amdgcn_mfma_f32_16x16x32_bf16(a, bb, sacc, 0, 0, 0);
        }
        if (wv == 0) {
            #pragma unroll
            for (int r = 0; r < 4; ++r) {
                const int l = qd * 4 + r;
                As_p[l][mc] = (2 * mc + 1 <= 16 * h + l) ? f2bf(sacc[r])
                                                         : (ushort_t)0;
            }
        }
    }

    // main contraction
    f32x4 acc[4];
    #pragma unroll
    for (int i = 0; i < 4; ++i) acc[i] = (f32x4){0.f, 0.f, 0.f, 0.f};
    #pragma unroll
    for (int i = 0; i < 4; ++i) {
        const int d0 = wv * 64 + i * 16;
        #pragma unroll
        for (int ks = 0; ks < 2; ++ks) {
            const bf16x8 a  = *(const bf16x8*)&As_ph[mc][ks * 32 + qd * 8];
            const bf16x8 bb = *(const bf16x8*)&Bs_m[d0 + mc][ks * 32 + qd * 8];
            acc[i] = __builtin_amdgcn_mfma_f32_16x16x32_bf16(a, bb, acc[i], 0, 0, 0);
        }
    }
    __syncthreads();

    // within-chunk correction
    {
        const bf16x8 a2 = *(const bf16x8*)&As_p[mc][qd * 8];
        #pragma unroll
        for (int i = 0; i < 4; ++i) {
            const int d0 = wv * 64 + i * 16;
            const bf16x8 b2 = *(const bf16x8*)&Bs_v[d0 + mc][qd * 8];
            acc[i] = __builtin_amdgcn_mfma_f32_16x16x32_bf16(a2, b2, acc[i], 0, 0, 0);
        }
    }

    // scale -> ref
    #pragma unroll
    for (int r = 0; r < 4; ++r) {
        const int l = qd * 4 + r;
        int va = (l0g + l + 1) >> 1; if (va < 1) va = 1;
        const float sc = 0.17677669529663687f * rsqrtf((float)va);
        #pragma unroll
        for (int i = 0; i < 4; ++i)
            ref[l][wv * 64 + i * 16 + mc] = acc[i][r] * sc;
    }
    __syncthreads();

    // LN1 -> rhat bf16
    {
        const int row = tid >> 4, cg = (tid & 15) * 16;
        float s = 0.f, sq = 0.f;
        #pragma unroll
        for (int i = 0; i < 16; ++i) {
            const float v = ref[row][cg + i];
            s += v; sq += v * v;
        }
        s += __shfl_xor(s, 1, 16);  sq += __shfl_xor(sq, 1, 16);
        s += __shfl_xor(s, 2, 16);  sq += __shfl_xor(sq, 2, 16);
        s += __shfl_xor(s, 4, 16);  sq += __shfl_xor(sq, 4, 16);
        s += __shfl_xor(s, 8, 16);  sq += __shfl_xor(sq, 8, 16);
        const float m = s * (1.f / 256.f);
        const float inv = rsqrtf(sq * (1.f / 256.f) - m * m + 1e-5f);
        ushort_t o16[16];
        #pragma unroll
        for (int i = 0; i < 16; ++i) {
            const int cc = cg + i;
            o16[i] = f2bf((ref[row][cc] - m) * inv * ln1_g[cc] + ln1_b[cc]);
        }
        ushort_t* dst = &rhat[(rowbase + row) * DD + cg];
        *(uint4*)&dst[0] = *(uint4*)&o16[0];
        *(uint4*)&dst[8] = *(uint4*)&o16[8];
    }
}

// ---------------------------------------------------------------------------
// gemm1: h = gelu(rhat @ W1^T + b1). BM=32, grid 1024.
// ---------------------------------------------------------------------------
__global__ __launch_bounds__(256) void gemm1_kernel(
    const ushort_t* __restrict__ A, const ushort_t* __restrict__ Bt,
    const float* __restrict__ bias, ushort_t* __restrict__ out)
{
    __shared__ ushort_t As[32][136];
    __shared__ ushort_t Bs[64][136];
    const int tid = threadIdx.x;
    const int mt = blockIdx.x & 127;
    const int nt = blockIdx.x >> 7;
    const int m0 = mt * 32, n0 = nt * 64;
    const int wv = tid >> 6, lane = tid & 63;
    const int qd = lane >> 4, mc = lane & 15;

    f32x4 acc0 = {0.f, 0.f, 0.f, 0.f};
    f32x4 acc1 = {0.f, 0.f, 0.f, 0.f};

    const int ar = tid >> 3, ak = (tid & 7) * 16;
    const int bn = tid >> 2, bk = (tid & 3) * 32;

    for (int k0 = 0; k0 < 256; k0 += 128) {
        __syncthreads();
        {
            const ushort_t* sa = &A[(long)(m0 + ar) * 256 + k0 + ak];
            *(uint4*)&As[ar][ak]     = *(const uint4*)&sa[0];
            *(uint4*)&As[ar][ak + 8] = *(const uint4*)&sa[8];
        }
        {
            const ushort_t* src = &Bt[(long)(n0 + bn) * 256 + k0 + bk];
            *(uint4*)&Bs[bn][bk +  0] = *(const uint4*)&src[0];
            *(uint4*)&Bs[bn][bk +  8] = *(const uint4*)&src[8];
            *(uint4*)&Bs[bn][bk + 16] = *(const uint4*)&src[16];
            *(uint4*)&Bs[bn][bk + 24] = *(const uint4*)&src[24];
        }
        __syncthreads();
        #pragma unroll
        for (int ko = 0; ko < 128; ko += 32) {
            const bf16x8 a0 = *(const bf16x8*)&As[mc][ko + qd * 8];
            const bf16x8 a1 = *(const bf16x8*)&As[16 + mc][ko + qd * 8];
            const bf16x8 b  = *(const bf16x8*)&Bs[wv * 16 + mc][ko + qd * 8];
            acc0 = __builtin_amdgcn_mfma_f32_16x16x32_bf16(a0, b, acc0, 0, 0, 0);
            acc1 = __builtin_amdgcn_mfma_f32_16x16x32_bf16(a1, b, acc1, 0, 0, 0);
        }
    }

    const int nn = n0 + wv * 16 + mc;
    const float bb = bias[nn];
    #pragma unroll
    for (int r = 0; r < 4; ++r) {
        const long row0w = m0 + qd * 4 + r;
        float v0 = acc0[r] + bb;
        float v1 = acc1[r] + bb;
        v0 = 0.5f * v0 * (1.f + erff(v0 * 0.70710678118654752f));
        v1 = 0.5f * v1 * (1.f + erff(v1 * 0.70710678118654752f));
        out[row0w * 512 + nn] = f2bf(v0);
        out[(row0w + 16) * 512 + nn] = f2bf(v1);
    }
}

// ---------------------------------------------------------------------------
// Kernel F: gemm2 + LN2 + gemm3 fused. BM=16, grid 256.
// ---------------------------------------------------------------------------
__global__ __launch_bounds__(256) void gemm23_kernel(
    const ushort_t* __restrict__ h, const ushort_t* __restrict__ W2t,
    const float* __restrict__ b2, const float* __restrict__ ln2_g,
    const float* __restrict__ ln2_b, const ushort_t* __restrict__ Wot,
    const float* __restrict__ bo, const float* __restrict__ x,
    float* __restrict__ out)
{
    __shared__ ushort_t As[16][72];
    __shared__ ushort_t Bs[256][72];
    __shared__ float Ct[16][264];
    __shared__ ushort_t shT[16][264];

    const int tid = threadIdx.x;
    const int m0 = blockIdx.x * 16;
    const int wv = tid >> 6, lane = tid & 63;
    const int qd = lane >> 4, mc = lane & 15;

    f32x4 acc[4];
    #pragma unroll
    for (int nf = 0; nf < 4; ++nf) acc[nf] = (f32x4){0.f,0.f,0.f,0.f};

    const int sr = tid >> 3, sk = (tid & 7) * 8;

    for (int k0 = 0; k0 < 512; k0 += 64) {
        __syncthreads();
        if (tid < 128)
            *(uint4*)&As[sr][sk] = *(const uint4*)&h[(long)(m0 + sr) * 512 + k0 + sk];
        #pragma unroll
        for (int rr = 0; rr < 8; ++rr) {
            const int n = rr * 32 + (tid >> 3);
            *(uint4*)&Bs[n][sk] = *(const uint4*)&W2t[(long)n * 512 + k0 + sk];
        }
        __syncthreads();
        #pragma unroll
        for (int ks = 0; ks < 2; ++ks) {
            const bf16x8 a = *(const bf16x8*)&As[mc][ks * 32 + qd * 8];
            #pragma unroll
            for (int nf = 0; nf < 4; ++nf) {
                const bf16x8 b = *(const bf16x8*)&Bs[wv * 64 + nf * 16 + mc][ks * 32 + qd * 8];
                acc[nf] = __builtin_amdgcn_mfma_f32_16x16x32_bf16(a, b, acc[nf], 0, 0, 0);
            }
        }
    }

    #pragma unroll
    for (int nf = 0; nf < 4; ++nf) {
        const int n = wv * 64 + nf * 16 + mc;
        const float bb = b2[n];
        #pragma unroll
        for (int r = 0; r < 4; ++r)
            Ct[qd * 4 + r][n] = acc[nf][r] + bb;
    }
    __syncthreads();

    {
        const int row = tid >> 4, cg = (tid & 15) * 16;
        float s = 0.f, sq = 0.f;
        #pragma unroll
        for (int i = 0; i < 16; ++i) {
            const float v = Ct[row][cg + i];
            s += v; sq += v * v;
        }
        s  += __shfl_xor(s, 1, 16);  sq += __shfl_xor(sq, 1, 16);
        s  += __shfl_xor(s, 2, 16);  sq += __shfl_xor(sq, 2, 16);
        s  += __shfl_xor(s, 4, 16);  sq += __shfl_xor(sq, 4, 16);
        s  += __shfl_xor(s, 8, 16);  sq += __shfl_xor(sq, 8, 16);
        const float m = s * (1.f / 256.f);
        const float inv = rsqrtf(sq * (1.f / 256.f) - m * m + 1e-5f);
        #pragma unroll
        for (int i = 0; i < 16; ++i) {
            const int cc = cg + i;
            shT[row][cc] = f2bf((Ct[row][cc] - m) * inv * ln2_g[cc] + ln2_b[cc]);
        }
    }

    f32x4 acc2[4];
    #pragma unroll
    for (int nf = 0; nf < 4; ++nf) acc2[nf] = (f32x4){0.f,0.f,0.f,0.f};

    for (int k0 = 0; k0 < 256; k0 += 64) {
        __syncthreads();
        #pragma unroll
        for (int rr = 0; rr < 8; ++rr) {
            const int n = rr * 32 + (tid >> 3);
            *(uint4*)&Bs[n][sk] = *(const uint4*)&Wot[(long)n * 256 + k0 + sk];
        }
        __syncthreads();
        #pragma unroll
        for (int ks = 0; ks < 2; ++ks) {
            const bf16x8 a = *(const bf16x8*)&shT[mc][k0 + ks * 32 + qd * 8];
            #pragma unroll
            for (int nf = 0; nf < 4; ++nf) {
                const bf16x8 b = *(const bf16x8*)&Bs[wv * 64 + nf * 16 + mc][ks * 32 + qd * 8];
                acc2[nf] = __builtin_amdgcn_mfma_f32_16x16x32_bf16(a, b, acc2[nf], 0, 0, 0);
            }
        }
    }

    #pragma unroll
    for (int nf = 0; nf < 4; ++nf) {
        const int n = wv * 64 + nf * 16 + mc;
        const float bb = bo[n];
        #pragma unroll
        for (int r = 0; r < 4; ++r) {
            const long row = m0 + qd * 4 + r;
            out[row * DD + n] = acc2[nf][r] + bb + x[row * DD + n];
        }
    }
}

// ---------------------------------------------------------------------------
extern "C" void kernel_launch(void* const* d_in, const int* in_sizes, int n_in,
                              void* d_out, int out_size, void* d_ws, size_t ws_size,
                              hipStream_t stream)
{
    const float* x     = (const float*)d_in[0];
    const float* key_W = (const float*)d_in[1];
    const float* key_b = (const float*)d_in[2];
    const float* val_W = (const float*)d_in[3];
    const float* val_b = (const float*)d_in[4];
    const float* ln1_g = (const float*)d_in[5];
    const float* ln1_b = (const float*)d_in[6];
    const float* W1    = (const float*)d_in[7];
    const float* b1    = (const float*)d_in[8];
    const float* W2    = (const float*)d_in[9];
    const float* b2    = (const float*)d_in[10];
    const float* ln2_g = (const float*)d_in[11];
    const float* ln2_b = (const float*)d_in[12];
    const float* Wo    = (const float*)d_in[13];
    const float* bo    = (const float*)d_in[14];
    float* outp = (float*)d_out;

    float* ws = (float*)d_ws;
    float*  ph       = ws;                            // 262144 f32 (1 MB)
    ushort_t* Mt_b   = (ushort_t*)(ws + 262144);      // 2097152 us (4 MB)
    ushort_t* Mpre_b = Mt_b + 2097152;                // 2097152 us (4 MB)
    ushort_t* VoddT  = Mpre_b + 2097152;              // 524288 us (1 MB)
    ushort_t* rhat_b = VoddT + 524288;                // 1048576 us (2 MB)
    ushort_t* W1t    = rhat_b + 1048576;              // 131072 us
    ushort_t* W2t    = W1t + 131072;
    ushort_t* Wot    = W2t + 131072;
    ushort_t* valWt  = Wot + 65536;
    // reuse Mt_b after prefix:
    ushort_t* h_b    = Mt_b;                          // 4096x512 bf16 (4 MB)

    prep_key_kernel<<<352, 256, 0, stream>>>(W1, W2, Wo, val_W, x, key_W, key_b,
                                             W1t, W2t, Wot, valWt, (float2*)ph);
    valbind_kernel<<<512, 256, 0, stream>>>(x, (const float2*)ph, valWt, val_b,
                                            VoddT, Mt_b);
    prefix_kernel<<<512, 256, 0, stream>>>(Mt_b, Mpre_b);
    retrieve_kernel<<<256, 256, 0, stream>>>(ph, Mpre_b, VoddT, ln1_g, ln1_b, rhat_b);
    gemm1_kernel<<<1024, 256, 0, stream>>>(rhat_b, W1t, b1, h_b);
    gemm23_kernel<<<256, 256, 0, stream>>>(h_b, W2t, b2, ln2_g, ln2_b,
                                           Wot, bo, x, outp);
}